// Round 7
// baseline (379.125 us; speedup 1.0000x reference)
//
#include <hip/hip_runtime.h>
#include <math.h>

#define B_ 8
#define C_ 64
#define H_ 128
#define W_ 128
#define O_ 64
#define HW_ (H_ * W_)
#define OMS 29     // floats per om row (odd stride -> conflict-free b32)

typedef short    short8v __attribute__((ext_vector_type(8)));
typedef _Float16 half8v  __attribute__((ext_vector_type(8)));
typedef __fp16   fp16x2  __attribute__((ext_vector_type(2)));
typedef float    f32x4   __attribute__((ext_vector_type(4)));
typedef float    f32x16  __attribute__((ext_vector_type(16)));
typedef unsigned uint4v  __attribute__((ext_vector_type(4)));

// XOR-granule swizzle: row of 64 halfs = 8 granules of 16B; physical granule = logical ^ (row&7).
__device__ __forceinline__ int swz(int row, int col) {
    return (row << 6) + ((((col >> 3) ^ (row & 7)) << 3)) + (col & 7);
}

__device__ __forceinline__ unsigned pack_bf16_pair(unsigned u0, unsigned u1) {
    return (u1 & 0xffff0000u) | (u0 >> 16);
}
__device__ __forceinline__ void split_rtne(float v, short* hi, short* lo) {
    unsigned u = __float_as_uint(v);
    unsigned r = (u + 0x7fffu + ((u >> 16) & 1u)) & 0xffff0000u;
    *hi = (short)(r >> 16);
    float rem = v - __uint_as_float(r);
    unsigned u2 = __float_as_uint(rem);
    unsigned r2 = (u2 + 0x7fffu + ((u2 >> 16) & 1u));
    *lo = (short)(r2 >> 16);
}

// ws: Wch[64*576] f16 ([o][k*64+c]), Womhi/Womlo[32*576] bf16 ([n][tap*64+c])
__global__ void prep_weights(const float* __restrict__ wc,
                             const float* __restrict__ wo,
                             const float* __restrict__ wm,
                             _Float16* __restrict__ Wch,
                             short* __restrict__ Womhi, short* __restrict__ Womlo)
{
    int tid = blockIdx.x * blockDim.x + threadIdx.x;
    if (tid < 64 * 576) {
        int o = tid / 576, ck = tid % 576;
        int k = ck >> 6, c = ck & 63;
        Wch[tid] = (_Float16)wc[(o * 64 + c) * 9 + k];
    }
    if (tid < 32 * 576) {
        int n = tid / 576, tk = tid % 576;
        int tap = tk >> 6, c = tk & 63;
        float v = 0.f;
        if (n < 18)      v = wo[(n * 64 + c) * 9 + tap];
        else if (n < 27) v = wm[((n - 18) * 64 + c) * 9 + tap];
        split_rtne(v, &Womhi[tid], &Womlo[tid]);
    }
}

// waves_per_eu(4,4): pin the occupancy tier -> allocator free to use 512/4 = 128 VGPRs.
// (R6 post-mortem: without the max, allocator targeted 56-64 VGPRs and serialized the
//  gather batch into per-group s_waitcnt round-trips.)
__global__ __attribute__((amdgpu_flat_work_group_size(256, 256)))
__attribute__((amdgpu_waves_per_eu(4, 4))) void deform_mfma(
    const float* __restrict__ x,
    const _Float16* __restrict__ Wch,
    const short* __restrict__ Womhi, const short* __restrict__ Womlo,
    float* __restrict__ out)
{
    __shared__ _Float16 sb[2][64 * 64];   // phase A: [0]=hi,[1]=lo; phase B: double buffer (16 KB)
    __shared__ float omb[64 * OMS];

    const int t = threadIdx.x;
    const int lane = t & 63;
    const int wv = t >> 6;
    const int px = lane;
    const int g = __builtin_amdgcn_readfirstlane(wv);

    const int blk = blockIdx.x;
    const int b = blk & 7;                 // XCD-batch swizzle (R5: FETCH 860->17 MB)
    const int rest = blk >> 3;
    const int wcol0 = (rest & 1) << 6;
    const int h = rest >> 1;
    const float* xb = x + (size_t)b * C_ * HW_;
    const float* xg = xb + (size_t)(g * 16) * HW_;   // wave-uniform channel-group base
    const int wcol = wcol0 + px;

    // ================= phase A: offset/mask conv via MFMA (bf16x3) =========
    f32x4 cv0 = {}, cv1 = {};
    float av[16];
    float okn;
    {
        int yy = h - 1, xx = wcol - 1;
        okn = (((unsigned)yy < (unsigned)H_) && ((unsigned)xx < (unsigned)W_)) ? 1.f : 0.f;
        int yyc = min(max(yy, 0), H_ - 1), xxc = min(max(xx, 0), W_ - 1);
        int voff = yyc * W_ + xxc;
#pragma unroll
        for (int j = 0; j < 16; ++j) av[j] = xg[(size_t)j * HW_ + voff];
    }
    const int mrowA = (wv << 4) + (lane & 15);
    const int kqA = (lane >> 4) << 3;
    const int n0 = lane & 15;

#pragma unroll 1
    for (int tap = 0; tap < 9; ++tap) {
        const float okc = okn;
#pragma unroll
        for (int i = 0; i < 4; ++i) {
            float s0 = av[4*i+0] * okc, s1 = av[4*i+1] * okc;
            float s2 = av[4*i+2] * okc, s3 = av[4*i+3] * okc;
            unsigned u0 = __float_as_uint(s0), u1 = __float_as_uint(s1);
            unsigned u2 = __float_as_uint(s2), u3 = __float_as_uint(s3);
            uint2 hv, lv;
            hv.x = pack_bf16_pair(u0, u1);
            hv.y = pack_bf16_pair(u2, u3);
            lv.x = pack_bf16_pair(__float_as_uint(s0 - __uint_as_float(u0 & 0xffff0000u)),
                                  __float_as_uint(s1 - __uint_as_float(u1 & 0xffff0000u)));
            lv.y = pack_bf16_pair(__float_as_uint(s2 - __uint_as_float(u2 & 0xffff0000u)),
                                  __float_as_uint(s3 - __uint_as_float(u3 & 0xffff0000u)));
            const int off = swz(px, (g << 4) + (i << 2));
            *(uint2*)&sb[0][off] = hv;
            *(uint2*)&sb[1][off] = lv;
        }
        if (tap < 8) {   // prefetch next tap's (coalesced) loads; fly across barrier
            int tn = tap + 1, ty = tn / 3, tx = tn - ty * 3;
            int yy = h + ty - 1, xx = wcol + tx - 1;
            okn = (((unsigned)yy < (unsigned)H_) && ((unsigned)xx < (unsigned)W_)) ? 1.f : 0.f;
            int yyc = min(max(yy, 0), H_ - 1), xxc = min(max(xx, 0), W_ - 1);
            int voff = yyc * W_ + xxc;
#pragma unroll
            for (int j = 0; j < 16; ++j) av[j] = xg[(size_t)j * HW_ + voff];
        }
        __builtin_amdgcn_s_waitcnt(0xC07F);   // lgkmcnt(0) only — vm loads stay in flight
        __builtin_amdgcn_s_barrier();
#pragma unroll
        for (int s = 0; s < 2; ++s) {
            const int koff = (s << 5) + kqA;
            short8v ahi = *(const short8v*)&sb[0][swz(mrowA, koff)];
            short8v alo = *(const short8v*)&sb[1][swz(mrowA, koff)];
            const int kg = tap * 64 + koff;
            short8v bh0 = *(const short8v*)&Womhi[n0 * 576 + kg];
            short8v bl0 = *(const short8v*)&Womlo[n0 * 576 + kg];
            short8v bh1 = *(const short8v*)&Womhi[(n0 + 16) * 576 + kg];
            short8v bl1 = *(const short8v*)&Womlo[(n0 + 16) * 576 + kg];
            cv0 = __builtin_amdgcn_mfma_f32_16x16x32_bf16(ahi, bh0, cv0, 0, 0, 0);
            cv0 = __builtin_amdgcn_mfma_f32_16x16x32_bf16(ahi, bl0, cv0, 0, 0, 0);
            cv0 = __builtin_amdgcn_mfma_f32_16x16x32_bf16(alo, bh0, cv0, 0, 0, 0);
            cv1 = __builtin_amdgcn_mfma_f32_16x16x32_bf16(ahi, bh1, cv1, 0, 0, 0);
            cv1 = __builtin_amdgcn_mfma_f32_16x16x32_bf16(ahi, bl1, cv1, 0, 0, 0);
            cv1 = __builtin_amdgcn_mfma_f32_16x16x32_bf16(alo, bh1, cv1, 0, 0, 0);
        }
        __builtin_amdgcn_s_barrier();   // reads consumed -> safe rewrite
    }

    // scatter om (C-layout: col=lane&15 -> j, row=(lane>>4)*4+r -> px-within-16)
    {
        const int j0 = lane & 15;
        const int pxo = (wv << 4) + ((lane >> 4) << 2);
#pragma unroll
        for (int r = 0; r < 4; ++r) {
            omb[(pxo + r) * OMS + j0] = cv0[r];
            if (j0 < 13) omb[(pxo + r) * OMS + j0 + 16] = cv1[r];
        }
    }
    __builtin_amdgcn_s_waitcnt(0xC07F);
    __builtin_amdgcn_s_barrier();

    // ================= phase B: sampling + einsum (fp16 MFMA, pipelined) ====
    f32x16 acc = {};
    const int mhalf = wv & 1, nhalf = wv >> 1;
    const int mrow = (mhalf << 5) + (lane & 31);
    const int nrow = (nhalf << 5) + (lane & 31);
    const int kq2 = (lane >> 5) << 3;

    unsigned pnl[8];   // packed fp16 samples for the upcoming tap

    auto sample_tap = [&](int k) {
        const float offy = omb[px * OMS + 2 * k];
        const float offx = omb[px * OMS + 2 * k + 1];
        const float mr = omb[px * OMS + 18 + k];
        const float mk = 1.f / (1.f + __expf(-mr));
        const int ki = k / 3, kj = k - ki * 3;
        const float py = (float)(h + ki - 1) + offy;
        const float pxf = (float)(wcol + kj - 1) + offx;
        const float y0f = floorf(py), x0f = floorf(pxf);
        const int y0i = (int)y0f, x0i = (int)x0f;
        const int y1i = y0i + 1, x1i = x0i + 1;
        const float wy1 = py - y0f, wy0 = 1.f - wy1;
        const float wx1 = pxf - x0f, wx0 = 1.f - wx1;
        const bool vy0 = (unsigned)y0i < (unsigned)H_;
        const bool vy1 = (unsigned)y1i < (unsigned)H_;
        const bool vx0 = (unsigned)x0i < (unsigned)W_;
        const bool vx1 = (unsigned)x1i < (unsigned)W_;
        const int y0c = min(max(y0i, 0), H_ - 1), y1c = min(max(y1i, 0), H_ - 1);
        const int x0c = min(max(x0i, 0), W_ - 1), x1c = min(max(x1i, 0), W_ - 1);
        const float w00 = wy0 * wx0 * ((vy0 && vx0) ? mk : 0.f);
        const float w01 = wy0 * wx1 * ((vy0 && vx1) ? mk : 0.f);
        const float w10 = wy1 * wx0 * ((vy1 && vx0) ? mk : 0.f);
        const float w11 = wy1 * wx1 * ((vy1 && vx1) ? mk : 0.f);
        const int i00 = y0c * W_ + x0c;
        const int i01 = y0c * W_ + x1c;
        const int i10 = y1c * W_ + x0c;
        const int i11 = y1c * W_ + x1c;

        // Flat 64-load batch: all gathers issued back-to-back, ONE vmcnt drain at
        // first use. Needs ~104 live VGPRs -> enabled by waves_per_eu(4,4).
        float tb[64];
#pragma unroll
        for (int j = 0; j < 16; ++j) {
            const float* bj = xg + (size_t)j * HW_;
            tb[4*j+0] = bj[i00]; tb[4*j+1] = bj[i01];
            tb[4*j+2] = bj[i10]; tb[4*j+3] = bj[i11];
        }
#pragma unroll
        for (int c = 0; c < 4; ++c) {
            float s0 = w00*tb[16*c+0]  + w01*tb[16*c+1]  + w10*tb[16*c+2]  + w11*tb[16*c+3];
            float s1 = w00*tb[16*c+4]  + w01*tb[16*c+5]  + w10*tb[16*c+6]  + w11*tb[16*c+7];
            float s2 = w00*tb[16*c+8]  + w01*tb[16*c+9]  + w10*tb[16*c+10] + w11*tb[16*c+11];
            float s3 = w00*tb[16*c+12] + w01*tb[16*c+13] + w10*tb[16*c+14] + w11*tb[16*c+15];
            fp16x2 p01 = __builtin_amdgcn_cvt_pkrtz(s0, s1);
            fp16x2 p23 = __builtin_amdgcn_cvt_pkrtz(s2, s3);
            pnl[2*c]   = __builtin_bit_cast(unsigned, p01);
            pnl[2*c+1] = __builtin_bit_cast(unsigned, p23);
        }
    };

    sample_tap(0);
#pragma unroll 1
    for (int k = 0; k < 9; ++k) {
        _Float16* sbw = sb[k & 1];
        uint4v pa = {pnl[0], pnl[1], pnl[2], pnl[3]};
        uint4v pb = {pnl[4], pnl[5], pnl[6], pnl[7]};
        *(uint4v*)&sbw[swz(px, (g << 4))]     = pa;
        *(uint4v*)&sbw[swz(px, (g << 4) + 8)] = pb;
        if (k < 8) sample_tap(k + 1);         // next tap's 64 gathers fly across barrier+MFMA
        __builtin_amdgcn_s_waitcnt(0xC07F);   // lgkm only — vm loads keep flying
        __builtin_amdgcn_s_barrier();
        const _Float16* sbr = sb[k & 1];
#pragma unroll
        for (int s = 0; s < 4; ++s) {
            const int koff = (s << 4) + kq2;
            half8v a  = *(const half8v*)&sbr[swz(mrow, koff)];
            half8v bw = *(const half8v*)&Wch[nrow * 576 + k * 64 + koff];
            acc = __builtin_amdgcn_mfma_f32_32x32x16_f16(a, bw, acc, 0, 0, 0);
        }
        // no trailing barrier: buf[k&1] next overwritten at k+2, after barrier k+1
    }

    // ================= epilogue: store C (32x32 layout, verified R3) =======
    {
        float* ob = out + ((size_t)b * O_ + nrow) * HW_ + h * W_ + wcol0;
        const int rbase = ((lane >> 5) << 2) + (mhalf << 5);
#pragma unroll
        for (int q = 0; q < 4; ++q) {
            f32x4 vv = {acc[4*q], acc[4*q+1], acc[4*q+2], acc[4*q+3]};
            *(f32x4*)&ob[rbase + 8*q] = vv;
        }
    }
}

extern "C" void kernel_launch(void* const* d_in, const int* in_sizes, int n_in,
                              void* d_out, int out_size, void* d_ws, size_t ws_size,
                              hipStream_t stream) {
    const float* x      = (const float*)d_in[0];
    const float* w_conv = (const float*)d_in[1];
    const float* w_off  = (const float*)d_in[2];
    const float* w_msk  = (const float*)d_in[3];
    float* out = (float*)d_out;

    _Float16* Wch = (_Float16*)d_ws;          // 64*576 halfs
    short* Womhi  = (short*)(Wch + 64 * 576); // 32*576
    short* Womlo  = Womhi + 32 * 576;

    prep_weights<<<144, 256, 0, stream>>>(w_conv, w_off, w_msk, Wch, Womhi, Womlo);

    deform_mfma<<<2048, 256, 0, stream>>>(x, Wch, Womhi, Womlo, out);
}